// Round 8
// baseline (215.195 us; speedup 1.0000x reference)
//
#include <hip/hip_runtime.h>

#define N_NODES 50000
#define N_EDGES 800000
#define HDIM    128
#define NGRAPH  8
#define NCLS    5
#define SCAN_CHUNK 1024
#define NSCANBLK ((N_NODES + SCAN_CHUNK - 1) / SCAN_CHUNK)   // 49

// ---- bf16 helpers (raw ushort storage, fp32 compute) ------------------------
__device__ __forceinline__ float bf2f(ushort u) {
    return __uint_as_float((unsigned int)u << 16);
}
__device__ __forceinline__ ushort f2bf(float f) {
    unsigned int u = __float_as_uint(f);
    u += 0x7FFFu + ((u >> 16) & 1u);      // round-to-nearest-even
    return (ushort)(u >> 16);
}

typedef __attribute__((ext_vector_type(8)))  __bf16 bf16x8;
typedef __attribute__((ext_vector_type(16))) float  f32x16;
union BF8 { uint4 q; ushort u[8]; bf16x8 v; };

// ------- init: zero cnti/hG + convert W1,W2 -> transposed bf16 Wt[c][k] ------
__global__ __launch_bounds__(256) void k_init(const float* __restrict__ W1,
                                              const float* __restrict__ W2,
                                              ushort* __restrict__ Wt1,
                                              ushort* __restrict__ Wt2,
                                              int* cnti, float* hG) {
    int i = blockIdx.x * blockDim.x + threadIdx.x;
    if (i < N_NODES) cnti[i] = 0;
    if (i < NGRAPH * 2 * HDIM) hG[i] = 0.0f;
    if (i < HDIM * HDIM) {
        int k = i >> 7, c = i & (HDIM - 1);          // read W[k][c] coalesced
        Wt1[c * HDIM + k] = f2bf(W1[i]);
        Wt2[c * HDIM + k] = f2bf(W2[i]);
    }
}

// ------- in-degree count AND per-edge slot assignment (one atomic pass) ------
__global__ __launch_bounds__(256) void k_count(const int* __restrict__ dst,
                                               int* cnti,
                                               ushort* __restrict__ slot16) {
    int e = blockIdx.x * blockDim.x + threadIdx.x;
    if (e < N_EDGES)
        slot16[e] = (ushort)atomicAdd(&cnti[dst[e]], 1);
}

// -------- scan step 1: block-local exclusive scan (1024/block) + dinv --------
__global__ __launch_bounds__(256) void k_scan1(const int* __restrict__ cnti,
                                               int* __restrict__ rowptr,
                                               int* __restrict__ bsum,
                                               float* __restrict__ dinv) {
    __shared__ int wsum[4];
    int tid = threadIdx.x, lane = tid & 63, wid = tid >> 6;
    int i0 = blockIdx.x * SCAN_CHUNK + tid * 4;
    int v[4];
    int tsum = 0;
#pragma unroll
    for (int p = 0; p < 4; ++p) {
        int i = i0 + p;
        v[p] = (i < N_NODES) ? cnti[i] : 0;
        if (i < N_NODES) dinv[i] = rsqrtf(1.0f + (float)v[p]);
        tsum += v[p];
    }
    int sc = tsum;
#pragma unroll
    for (int off = 1; off < 64; off <<= 1) {
        int t = __shfl_up(sc, off, 64);
        if (lane >= off) sc += t;
    }
    if (lane == 63) wsum[wid] = sc;
    __syncthreads();
    int woff = 0;
    for (int w = 0; w < wid; ++w) woff += wsum[w];
    int excl = woff + sc - tsum;
#pragma unroll
    for (int p = 0; p < 4; ++p) {
        int i = i0 + p;
        if (i < N_NODES) rowptr[i] = excl;
        excl += v[p];
    }
    if (tid == 255) bsum[blockIdx.x] = woff + sc;   // block total
}

// -------- scan step 2: one wave scans the 49 block totals (in place) ---------
__global__ __launch_bounds__(64) void k_scan2(int* __restrict__ bsum,
                                              int* __restrict__ rowptr) {
    int t = threadIdx.x;
    int v = (t < NSCANBLK) ? bsum[t] : 0;
    int sc = v;
#pragma unroll
    for (int off = 1; off < 64; off <<= 1) {
        int x = __shfl_up(sc, off, 64);
        if (t >= off) sc += x;
    }
    if (t < NSCANBLK) bsum[t] = sc - v;             // exclusive offset
    if (t == NSCANBLK - 1) rowptr[N_NODES] = sc;    // grand total (=N_EDGES)
}

// -------- scan step 3: add block offsets --------------------------------------
__global__ __launch_bounds__(256) void k_scan3(int* __restrict__ rowptr,
                                               const int* __restrict__ bsum) {
    int i = blockIdx.x * blockDim.x + threadIdx.x;
    if (i < N_NODES) rowptr[i] += bsum[i >> 10];
}

// ---------------- fill CSR: atomic-free, 2B scatter --------------------------
__global__ __launch_bounds__(256) void k_fill(const int* __restrict__ src,
                                              const int* __restrict__ dst,
                                              const int* __restrict__ rowptr,
                                              const ushort* __restrict__ slot16,
                                              ushort* __restrict__ csrc16) {
    int e = blockIdx.x * blockDim.x + threadIdx.x;
    if (e < N_EDGES) {
        int d = dst[e];
        int pos = rowptr[d] + (int)slot16[e];
        csrc16[pos] = (ushort)src[e];
    }
}

// ---------------- MFMA GEMM: Y_bf16 = dinv[r] * (X @ W), no LDS --------------
// Wt is transposed bf16 weights: Wt[c][k]. T = float (layer 1) or ushort (bf16).
template <typename T>
__global__ __launch_bounds__(256) void k_gemm_mfma(const T* __restrict__ X,
                                                   const ushort* __restrict__ Wt,
                                                   const float* __restrict__ dinv,
                                                   ushort* __restrict__ Y) {
    int tid  = threadIdx.x;
    int lane = tid & 63;
    int wv   = tid >> 6;            // 0..3
    int c0   = wv * 32;
    int lrow = lane & 31;           // A-row / C-col offset
    int kgrp = lane >> 5;           // 0..1

    // B-frag: lane holds Wt[c0+lrow][kc*16 + kgrp*8 .. +7] -- one 16B load each
    bf16x8 bfrag[8];
    {
        const ushort* wp = Wt + (size_t)(c0 + lrow) * HDIM + kgrp * 8;
#pragma unroll
        for (int kc = 0; kc < 8; ++kc) {
            BF8 t;
            t.q = *reinterpret_cast<const uint4*>(wp + kc * 16);
            bfrag[kc] = t.v;
        }
    }

#pragma unroll
    for (int chunk = 0; chunk < 2; ++chunk) {
        int m0 = blockIdx.x * 64 + chunk * 32;
        if (m0 >= N_NODES) return;
        int arow = m0 + lrow;
        if (arow > N_NODES - 1) arow = N_NODES - 1;   // clamp tail loads
        const T* xp = X + (size_t)arow * HDIM + kgrp * 8;
        f32x16 acc;
#pragma unroll
        for (int i = 0; i < 16; ++i) acc[i] = 0.f;
#pragma unroll
        for (int kc = 0; kc < 8; ++kc) {
            BF8 a;
            if constexpr (sizeof(T) == 2) {
                a.q = *reinterpret_cast<const uint4*>(xp + kc * 16);
            } else {
                float4 f0 = *reinterpret_cast<const float4*>(xp + kc * 16);
                float4 f1 = *reinterpret_cast<const float4*>(xp + kc * 16 + 4);
                a.u[0] = f2bf(f0.x); a.u[1] = f2bf(f0.y);
                a.u[2] = f2bf(f0.z); a.u[3] = f2bf(f0.w);
                a.u[4] = f2bf(f1.x); a.u[5] = f2bf(f1.y);
                a.u[6] = f2bf(f1.z); a.u[7] = f2bf(f1.w);
            }
            acc = __builtin_amdgcn_mfma_f32_32x32x16_bf16(a.v, bfrag[kc], acc, 0, 0, 0);
        }
#pragma unroll
        for (int r = 0; r < 16; ++r) {
            int row = m0 + (r & 3) + 8 * (r >> 2) + 4 * kgrp;
            if (row < N_NODES)
                Y[(size_t)row * HDIM + c0 + lrow] = f2bf(acc[r] * dinv[row]);
        }
    }
}

// ---------------- aggregation: wave per node, 2 bf16 feats/lane, 8x unroll ---
__global__ __launch_bounds__(256) void k_agg(const ushort* __restrict__ y,
                                             const int* __restrict__ rowptr,
                                             const ushort* __restrict__ csrc16,
                                             const float* __restrict__ dinv,
                                             const float* __restrict__ bias,
                                             ushort* __restrict__ h) {
    int node = blockIdx.x * 4 + (threadIdx.x >> 6);
    if (node >= N_NODES) return;
    int lane = threadIdx.x & 63;
    int e0 = rowptr[node], e1 = rowptr[node + 1];
    float a0 = 0.f, a1 = 0.f, b0 = 0.f, b1 = 0.f;
    float c0 = 0.f, c1 = 0.f, d0 = 0.f, d1 = 0.f;
    int j = e0;
    for (; j + 8 <= e1; j += 8) {
        int s0 = csrc16[j],     s1 = csrc16[j + 1], s2 = csrc16[j + 2], s3 = csrc16[j + 3];
        int s4 = csrc16[j + 4], s5 = csrc16[j + 5], s6 = csrc16[j + 6], s7 = csrc16[j + 7];
        ushort2 v0 = *reinterpret_cast<const ushort2*>(y + (size_t)s0 * HDIM + lane * 2);
        ushort2 v1 = *reinterpret_cast<const ushort2*>(y + (size_t)s1 * HDIM + lane * 2);
        ushort2 v2 = *reinterpret_cast<const ushort2*>(y + (size_t)s2 * HDIM + lane * 2);
        ushort2 v3 = *reinterpret_cast<const ushort2*>(y + (size_t)s3 * HDIM + lane * 2);
        ushort2 v4 = *reinterpret_cast<const ushort2*>(y + (size_t)s4 * HDIM + lane * 2);
        ushort2 v5 = *reinterpret_cast<const ushort2*>(y + (size_t)s5 * HDIM + lane * 2);
        ushort2 v6 = *reinterpret_cast<const ushort2*>(y + (size_t)s6 * HDIM + lane * 2);
        ushort2 v7 = *reinterpret_cast<const ushort2*>(y + (size_t)s7 * HDIM + lane * 2);
        a0 += bf2f(v0.x) + bf2f(v4.x); a1 += bf2f(v0.y) + bf2f(v4.y);
        b0 += bf2f(v1.x) + bf2f(v5.x); b1 += bf2f(v1.y) + bf2f(v5.y);
        c0 += bf2f(v2.x) + bf2f(v6.x); c1 += bf2f(v2.y) + bf2f(v6.y);
        d0 += bf2f(v3.x) + bf2f(v7.x); d1 += bf2f(v3.y) + bf2f(v7.y);
    }
    for (; j + 4 <= e1; j += 4) {
        int s0 = csrc16[j], s1 = csrc16[j + 1], s2 = csrc16[j + 2], s3 = csrc16[j + 3];
        ushort2 v0 = *reinterpret_cast<const ushort2*>(y + (size_t)s0 * HDIM + lane * 2);
        ushort2 v1 = *reinterpret_cast<const ushort2*>(y + (size_t)s1 * HDIM + lane * 2);
        ushort2 v2 = *reinterpret_cast<const ushort2*>(y + (size_t)s2 * HDIM + lane * 2);
        ushort2 v3 = *reinterpret_cast<const ushort2*>(y + (size_t)s3 * HDIM + lane * 2);
        a0 += bf2f(v0.x); a1 += bf2f(v0.y);
        b0 += bf2f(v1.x); b1 += bf2f(v1.y);
        c0 += bf2f(v2.x); c1 += bf2f(v2.y);
        d0 += bf2f(v3.x); d1 += bf2f(v3.y);
    }
    for (; j < e1; ++j) {
        int s = csrc16[j];
        ushort2 v = *reinterpret_cast<const ushort2*>(y + (size_t)s * HDIM + lane * 2);
        a0 += bf2f(v.x); a1 += bf2f(v.y);
    }
    ushort2 vs = *reinterpret_cast<const ushort2*>(y + (size_t)node * HDIM + lane * 2);
    a0 += bf2f(vs.x); a1 += bf2f(vs.y);
    float s0 = (a0 + b0) + (c0 + d0);
    float s1 = (a1 + b1) + (c1 + d1);
    float di = dinv[node];
    float r0 = fmaxf(fmaf(s0, di, bias[lane * 2]),     0.f);
    float r1 = fmaxf(fmaf(s1, di, bias[lane * 2 + 1]), 0.f);
    ushort2 res; res.x = f2bf(r0); res.y = f2bf(r1);
    *reinterpret_cast<ushort2*>(h + (size_t)node * HDIM + lane * 2) = res;
}

// ---------------- mean-pool: sorted batch, run-length partial sums -----------
__global__ __launch_bounds__(256) void k_pool(const ushort* __restrict__ h2,
                                              const ushort* __restrict__ h1,
                                              const int* __restrict__ batch,
                                              float* __restrict__ hG) {
    int f  = threadIdx.x;                       // 0..255 (h2 | h1 concat)
    const ushort* srcp = (f < HDIM) ? h2 : h1;
    int ff = f & (HDIM - 1);
    int n0 = blockIdx.x * 64;
    int n1 = min(n0 + 64, N_NODES);
    int g = batch[n0];
    float run = 0.f;
    for (int n = n0; n < n1; ++n) {
        int gn = batch[n];
        if (gn != g) {
            atomicAdd(&hG[g * 256 + f], run);
            run = 0.f;
            g = gn;
        }
        run += bf2f(srcp[(size_t)n * HDIM + ff]);
    }
    atomicAdd(&hG[g * 256 + f], run);
}

// ---------------- finalize: counts via binary search (batch sorted), ---------
__global__ __launch_bounds__(256) void k_final(const float* __restrict__ hG,
                                               const int* __restrict__ batch,
                                               const float* __restrict__ Wl,
                                               const float* __restrict__ bl,
                                               float* __restrict__ outp) {
    __shared__ float sH[NGRAPH * 2 * HDIM];
    __shared__ float sL[NGRAPH * NCLS];
    __shared__ int   sStart[NGRAPH + 1];
    int tid = threadIdx.x;
    if (tid <= NGRAPH) {
        int lo = 0, hi = N_NODES;
        while (lo < hi) {
            int mid = (lo + hi) >> 1;
            if (batch[mid] < tid) lo = mid + 1; else hi = mid;
        }
        sStart[tid] = lo;
    }
    __syncthreads();
    for (int i = tid; i < NGRAPH * 2 * HDIM; i += 256) {
        int g = i >> 8;
        float cnt = (float)(sStart[g + 1] - sStart[g]);
        float m = hG[i] / fmaxf(cnt, 1.0f);
        sH[i] = m;
        outp[i] = m;
    }
    __syncthreads();
    if (tid < NGRAPH * NCLS) {
        int g = tid / NCLS, c = tid % NCLS;
        float acc = bl[c];
        for (int k = 0; k < 2 * HDIM; ++k)
            acc += sH[g * 256 + k] * Wl[k * NCLS + c];
        sL[tid] = acc;
    }
    __syncthreads();
    if (tid < NGRAPH) {
        float mx = -1e30f;
        for (int c = 0; c < NCLS; ++c) mx = fmaxf(mx, sL[tid * NCLS + c]);
        float se = 0.f;
        for (int c = 0; c < NCLS; ++c) se += expf(sL[tid * NCLS + c] - mx);
        float lse = logf(se) + mx;
        for (int c = 0; c < NCLS; ++c)
            outp[NGRAPH * 2 * HDIM + tid * NCLS + c] = sL[tid * NCLS + c] - lse;
    }
}

extern "C" void kernel_launch(void* const* d_in, const int* in_sizes, int n_in,
                              void* d_out, int out_size, void* d_ws, size_t ws_size,
                              hipStream_t stream) {
    const float* x    = (const float*)d_in[0];
    const int*   eidx = (const int*)d_in[1];
    const int*   batch= (const int*)d_in[2];
    const float* W1   = (const float*)d_in[3];
    const float* b1   = (const float*)d_in[4];
    const float* W2   = (const float*)d_in[5];
    const float* b2   = (const float*)d_in[6];
    const float* Wl   = (const float*)d_in[7];
    const float* bl   = (const float*)d_in[8];
    float* outp = (float*)d_out;

    const int* src = eidx;             // edge_index[0]
    const int* dst = eidx + N_EDGES;   // edge_index[1]

    char* ws = (char*)d_ws;
    size_t off = 0;
    auto alloc = [&](size_t bytes) -> char* {
        char* p = ws + off;
        off += (bytes + 255) & ~(size_t)255;
        return p;
    };
    ushort* y     = (ushort*)alloc((size_t)N_NODES * HDIM * 2);
    ushort* h1    = (ushort*)alloc((size_t)N_NODES * HDIM * 2);
    ushort* h2    = (ushort*)alloc((size_t)N_NODES * HDIM * 2);
    ushort* Wt1   = (ushort*)alloc((size_t)HDIM * HDIM * 2);
    ushort* Wt2   = (ushort*)alloc((size_t)HDIM * HDIM * 2);
    float*  dinv  = (float*) alloc((size_t)N_NODES * 4);
    int*    cnti  = (int*)   alloc((size_t)N_NODES * 4);
    int*    rowptr= (int*)   alloc((size_t)(N_NODES + 1) * 4);
    int*    bsum  = (int*)   alloc((size_t)NSCANBLK * 4);
    ushort* slot16= (ushort*)alloc((size_t)N_EDGES * 2);
    ushort* csrc16= (ushort*)alloc((size_t)N_EDGES * 2);
    float*  hG    = (float*) alloc((size_t)NGRAPH * 2 * HDIM * 4);

    k_init <<<(N_NODES + 255) / 256, 256, 0, stream>>>(W1, W2, Wt1, Wt2, cnti, hG);
    k_count<<<(N_EDGES + 255) / 256, 256, 0, stream>>>(dst, cnti, slot16);
    k_scan1<<<NSCANBLK, 256, 0, stream>>>(cnti, rowptr, bsum, dinv);
    k_scan2<<<1, 64, 0, stream>>>(bsum, rowptr);
    k_scan3<<<(N_NODES + 255) / 256, 256, 0, stream>>>(rowptr, bsum);
    k_fill <<<(N_EDGES + 255) / 256, 256, 0, stream>>>(src, dst, rowptr, slot16, csrc16);

    k_gemm_mfma<float> <<<(N_NODES + 63) / 64, 256, 0, stream>>>(x, Wt1, dinv, y);
    k_agg              <<<(N_NODES + 3) / 4, 256, 0, stream>>>(y, rowptr, csrc16, dinv, b1, h1);
    k_gemm_mfma<ushort><<<(N_NODES + 63) / 64, 256, 0, stream>>>(h1, Wt2, dinv, y);
    k_agg              <<<(N_NODES + 3) / 4, 256, 0, stream>>>(y, rowptr, csrc16, dinv, b2, h2);

    k_pool <<<(N_NODES + 63) / 64, 256, 0, stream>>>(h2, h1, batch, hG);
    k_final<<<1, 256, 0, stream>>>(hG, batch, Wl, bl, outp);

    (void)in_sizes; (void)n_in; (void)out_size; (void)ws_size;
}

// Round 9
// 200.608 us; speedup vs baseline: 1.0727x; 1.0727x over previous
//
#include <hip/hip_runtime.h>

#define N_NODES 50000
#define N_EDGES 800000
#define HDIM    128
#define NGRAPH  8
#define NCLS    5
#define SCAN_CHUNK 1024
#define NSCANBLK ((N_NODES + SCAN_CHUNK - 1) / SCAN_CHUNK)   // 49
#define NB_GEMM  ((N_NODES + 63) / 64)                        // 782
#define NB_EDGE  ((N_EDGES + 255) / 256)                      // 3125

// ---- bf16 helpers (raw ushort storage, fp32 compute) ------------------------
__device__ __forceinline__ float bf2f(ushort u) {
    return __uint_as_float((unsigned int)u << 16);
}
__device__ __forceinline__ ushort f2bf(float f) {
    unsigned int u = __float_as_uint(f);
    u += 0x7FFFu + ((u >> 16) & 1u);      // round-to-nearest-even
    return (ushort)(u >> 16);
}

typedef __attribute__((ext_vector_type(8)))  __bf16 bf16x8;
typedef __attribute__((ext_vector_type(16))) float  f32x16;
union BF8 { uint4 q; ushort u[8]; bf16x8 v; };

// ------- pre: zero cnti/hG, x fp32->bf16, W1/W2 -> transposed bf16 -----------
__global__ __launch_bounds__(256) void k_pre(const float* __restrict__ x,
                                             ushort* __restrict__ xb,
                                             const float* __restrict__ W1,
                                             const float* __restrict__ W2,
                                             ushort* __restrict__ Wt1,
                                             ushort* __restrict__ Wt2,
                                             int* cnti, float* hG) {
    int i = blockIdx.x * blockDim.x + threadIdx.x;
    if (i < N_NODES) cnti[i] = 0;
    if (i < NGRAPH * 2 * HDIM) hG[i] = 0.0f;
    if (i < HDIM * HDIM) {
        int k = i >> 7, c = i & (HDIM - 1);          // read W[k][c] coalesced
        Wt1[c * HDIM + k] = f2bf(W1[i]);
        Wt2[c * HDIM + k] = f2bf(W2[i]);
    }
    if ((size_t)i * 8 < (size_t)N_NODES * HDIM) {
        float4 f0 = reinterpret_cast<const float4*>(x)[i * 2];
        float4 f1 = reinterpret_cast<const float4*>(x)[i * 2 + 1];
        uint4 o;
        o.x = (unsigned)f2bf(f0.x) | ((unsigned)f2bf(f0.y) << 16);
        o.y = (unsigned)f2bf(f0.z) | ((unsigned)f2bf(f0.w) << 16);
        o.z = (unsigned)f2bf(f1.x) | ((unsigned)f2bf(f1.y) << 16);
        o.w = (unsigned)f2bf(f1.z) | ((unsigned)f2bf(f1.w) << 16);
        reinterpret_cast<uint4*>(xb)[i] = o;
    }
}

// ------- in-degree count AND per-edge slot assignment (one atomic pass) ------
__global__ __launch_bounds__(256) void k_count(const int* __restrict__ dst,
                                               int* cnti,
                                               ushort* __restrict__ slot16) {
    int e = blockIdx.x * blockDim.x + threadIdx.x;
    if (e < N_EDGES)
        slot16[e] = (ushort)atomicAdd(&cnti[dst[e]], 1);
}

// -------- scan step 1: block-local exclusive scan (1024/block) + dinv --------
__global__ __launch_bounds__(256) void k_scan1(const int* __restrict__ cnti,
                                               int* __restrict__ rowptr,
                                               int* __restrict__ bsum,
                                               float* __restrict__ dinv) {
    __shared__ int wsum[4];
    int tid = threadIdx.x, lane = tid & 63, wid = tid >> 6;
    int i0 = blockIdx.x * SCAN_CHUNK + tid * 4;
    int v[4];
    int tsum = 0;
#pragma unroll
    for (int p = 0; p < 4; ++p) {
        int i = i0 + p;
        v[p] = (i < N_NODES) ? cnti[i] : 0;
        if (i < N_NODES) dinv[i] = rsqrtf(1.0f + (float)v[p]);
        tsum += v[p];
    }
    int sc = tsum;
#pragma unroll
    for (int off = 1; off < 64; off <<= 1) {
        int t = __shfl_up(sc, off, 64);
        if (lane >= off) sc += t;
    }
    if (lane == 63) wsum[wid] = sc;
    __syncthreads();
    int woff = 0;
    for (int w = 0; w < wid; ++w) woff += wsum[w];
    int excl = woff + sc - tsum;
#pragma unroll
    for (int p = 0; p < 4; ++p) {
        int i = i0 + p;
        if (i < N_NODES) rowptr[i] = excl;
        excl += v[p];
    }
    if (tid == 255) bsum[blockIdx.x] = woff + sc;   // block total
}

// -------- scan step 2: one wave scans the 49 block totals (in place) ---------
__global__ __launch_bounds__(64) void k_scan2(int* __restrict__ bsum,
                                              int* __restrict__ rowptr) {
    int t = threadIdx.x;
    int v = (t < NSCANBLK) ? bsum[t] : 0;
    int sc = v;
#pragma unroll
    for (int off = 1; off < 64; off <<= 1) {
        int x = __shfl_up(sc, off, 64);
        if (t >= off) sc += x;
    }
    if (t < NSCANBLK) bsum[t] = sc - v;             // exclusive offset
    if (t == NSCANBLK - 1) rowptr[N_NODES] = sc;    // grand total (=N_EDGES)
}

// -------- scan step 3: add block offsets --------------------------------------
__global__ __launch_bounds__(256) void k_scan3(int* __restrict__ rowptr,
                                               const int* __restrict__ bsum) {
    int i = blockIdx.x * blockDim.x + threadIdx.x;
    if (i < N_NODES) rowptr[i] += bsum[i >> 10];
}

// ---- fused: blocks [0,NB_GEMM) do gemm1 (xb@Wt1 -> y, NO dinv);  ------------
// ---- blocks [NB_GEMM, NB_GEMM+NB_EDGE) do CSR fill (atomic-free)  -----------
__global__ __launch_bounds__(256) void k_gemm_fill(const ushort* __restrict__ Xb,
                                                   const ushort* __restrict__ Wt,
                                                   ushort* __restrict__ Y,
                                                   const int* __restrict__ src,
                                                   const int* __restrict__ dst,
                                                   const int* __restrict__ rowptr,
                                                   const ushort* __restrict__ slot16,
                                                   ushort* __restrict__ csrc16) {
    if (blockIdx.x >= NB_GEMM) {
        // ---------------- fill path ----------------
        int e = (blockIdx.x - NB_GEMM) * 256 + threadIdx.x;
        if (e < N_EDGES) {
            int d = dst[e];
            int pos = rowptr[d] + (int)slot16[e];
            csrc16[pos] = (ushort)src[e];
        }
        return;
    }
    // ---------------- gemm path ----------------
    int tid  = threadIdx.x;
    int lane = tid & 63;
    int wv   = tid >> 6;            // 0..3
    int c0   = wv * 32;
    int lrow = lane & 31;
    int kgrp = lane >> 5;

    bf16x8 bfrag[8];
    {
        const ushort* wp = Wt + (size_t)(c0 + lrow) * HDIM + kgrp * 8;
#pragma unroll
        for (int kc = 0; kc < 8; ++kc) {
            BF8 t;
            t.q = *reinterpret_cast<const uint4*>(wp + kc * 16);
            bfrag[kc] = t.v;
        }
    }
#pragma unroll
    for (int chunk = 0; chunk < 2; ++chunk) {
        int m0 = blockIdx.x * 64 + chunk * 32;
        if (m0 >= N_NODES) return;
        int arow = m0 + lrow;
        if (arow > N_NODES - 1) arow = N_NODES - 1;
        const ushort* xp = Xb + (size_t)arow * HDIM + kgrp * 8;
        f32x16 acc;
#pragma unroll
        for (int i = 0; i < 16; ++i) acc[i] = 0.f;
#pragma unroll
        for (int kc = 0; kc < 8; ++kc) {
            BF8 a;
            a.q = *reinterpret_cast<const uint4*>(xp + kc * 16);
            acc = __builtin_amdgcn_mfma_f32_32x32x16_bf16(a.v, bfrag[kc], acc, 0, 0, 0);
        }
#pragma unroll
        for (int r = 0; r < 16; ++r) {
            int row = m0 + (r & 3) + 8 * (r >> 2) + 4 * kgrp;
            if (row < N_NODES)
                Y[(size_t)row * HDIM + c0 + lrow] = f2bf(acc[r]);
        }
    }
}

// ---------------- plain MFMA GEMM (layer 2): Y = X @ W, no dinv --------------
__global__ __launch_bounds__(256) void k_gemm(const ushort* __restrict__ Xb,
                                              const ushort* __restrict__ Wt,
                                              ushort* __restrict__ Y) {
    int tid  = threadIdx.x;
    int lane = tid & 63;
    int wv   = tid >> 6;
    int c0   = wv * 32;
    int lrow = lane & 31;
    int kgrp = lane >> 5;

    bf16x8 bfrag[8];
    {
        const ushort* wp = Wt + (size_t)(c0 + lrow) * HDIM + kgrp * 8;
#pragma unroll
        for (int kc = 0; kc < 8; ++kc) {
            BF8 t;
            t.q = *reinterpret_cast<const uint4*>(wp + kc * 16);
            bfrag[kc] = t.v;
        }
    }
#pragma unroll
    for (int chunk = 0; chunk < 2; ++chunk) {
        int m0 = blockIdx.x * 64 + chunk * 32;
        if (m0 >= N_NODES) return;
        int arow = m0 + lrow;
        if (arow > N_NODES - 1) arow = N_NODES - 1;
        const ushort* xp = Xb + (size_t)arow * HDIM + kgrp * 8;
        f32x16 acc;
#pragma unroll
        for (int i = 0; i < 16; ++i) acc[i] = 0.f;
#pragma unroll
        for (int kc = 0; kc < 8; ++kc) {
            BF8 a;
            a.q = *reinterpret_cast<const uint4*>(xp + kc * 16);
            acc = __builtin_amdgcn_mfma_f32_32x32x16_bf16(a.v, bfrag[kc], acc, 0, 0, 0);
        }
#pragma unroll
        for (int r = 0; r < 16; ++r) {
            int row = m0 + (r & 3) + 8 * (r >> 2) + 4 * kgrp;
            if (row < N_NODES)
                Y[(size_t)row * HDIM + c0 + lrow] = f2bf(acc[r]);
        }
    }
}

// ------- aggregation: wave/node; h = relu(dinv[d]*(Σ dinv[s]*xw[s] + dinv[d]*xw[d]) + b)
__global__ __launch_bounds__(256) void k_agg(const ushort* __restrict__ y,
                                             const int* __restrict__ rowptr,
                                             const ushort* __restrict__ csrc16,
                                             const float* __restrict__ dinv,
                                             const float* __restrict__ bias,
                                             ushort* __restrict__ h) {
    int node = blockIdx.x * 4 + (threadIdx.x >> 6);
    if (node >= N_NODES) return;
    int lane = threadIdx.x & 63;
    int e0 = rowptr[node], e1 = rowptr[node + 1];
    float a0 = 0.f, a1 = 0.f, b0 = 0.f, b1 = 0.f;
    float c0 = 0.f, c1 = 0.f, d0 = 0.f, d1 = 0.f;
    int j = e0;
    for (; j + 8 <= e1; j += 8) {
        int s0 = csrc16[j],     s1 = csrc16[j + 1], s2 = csrc16[j + 2], s3 = csrc16[j + 3];
        int s4 = csrc16[j + 4], s5 = csrc16[j + 5], s6 = csrc16[j + 6], s7 = csrc16[j + 7];
        float w0 = dinv[s0], w1 = dinv[s1], w2 = dinv[s2], w3 = dinv[s3];
        float w4 = dinv[s4], w5 = dinv[s5], w6 = dinv[s6], w7 = dinv[s7];
        ushort2 v0 = *reinterpret_cast<const ushort2*>(y + (size_t)s0 * HDIM + lane * 2);
        ushort2 v1 = *reinterpret_cast<const ushort2*>(y + (size_t)s1 * HDIM + lane * 2);
        ushort2 v2 = *reinterpret_cast<const ushort2*>(y + (size_t)s2 * HDIM + lane * 2);
        ushort2 v3 = *reinterpret_cast<const ushort2*>(y + (size_t)s3 * HDIM + lane * 2);
        ushort2 v4 = *reinterpret_cast<const ushort2*>(y + (size_t)s4 * HDIM + lane * 2);
        ushort2 v5 = *reinterpret_cast<const ushort2*>(y + (size_t)s5 * HDIM + lane * 2);
        ushort2 v6 = *reinterpret_cast<const ushort2*>(y + (size_t)s6 * HDIM + lane * 2);
        ushort2 v7 = *reinterpret_cast<const ushort2*>(y + (size_t)s7 * HDIM + lane * 2);
        a0 = fmaf(w0, bf2f(v0.x), a0); a1 = fmaf(w0, bf2f(v0.y), a1);
        b0 = fmaf(w1, bf2f(v1.x), b0); b1 = fmaf(w1, bf2f(v1.y), b1);
        c0 = fmaf(w2, bf2f(v2.x), c0); c1 = fmaf(w2, bf2f(v2.y), c1);
        d0 = fmaf(w3, bf2f(v3.x), d0); d1 = fmaf(w3, bf2f(v3.y), d1);
        a0 = fmaf(w4, bf2f(v4.x), a0); a1 = fmaf(w4, bf2f(v4.y), a1);
        b0 = fmaf(w5, bf2f(v5.x), b0); b1 = fmaf(w5, bf2f(v5.y), b1);
        c0 = fmaf(w6, bf2f(v6.x), c0); c1 = fmaf(w6, bf2f(v6.y), c1);
        d0 = fmaf(w7, bf2f(v7.x), d0); d1 = fmaf(w7, bf2f(v7.y), d1);
    }
    for (; j + 4 <= e1; j += 4) {
        int s0 = csrc16[j], s1 = csrc16[j + 1], s2 = csrc16[j + 2], s3 = csrc16[j + 3];
        float w0 = dinv[s0], w1 = dinv[s1], w2 = dinv[s2], w3 = dinv[s3];
        ushort2 v0 = *reinterpret_cast<const ushort2*>(y + (size_t)s0 * HDIM + lane * 2);
        ushort2 v1 = *reinterpret_cast<const ushort2*>(y + (size_t)s1 * HDIM + lane * 2);
        ushort2 v2 = *reinterpret_cast<const ushort2*>(y + (size_t)s2 * HDIM + lane * 2);
        ushort2 v3 = *reinterpret_cast<const ushort2*>(y + (size_t)s3 * HDIM + lane * 2);
        a0 = fmaf(w0, bf2f(v0.x), a0); a1 = fmaf(w0, bf2f(v0.y), a1);
        b0 = fmaf(w1, bf2f(v1.x), b0); b1 = fmaf(w1, bf2f(v1.y), b1);
        c0 = fmaf(w2, bf2f(v2.x), c0); c1 = fmaf(w2, bf2f(v2.y), c1);
        d0 = fmaf(w3, bf2f(v3.x), d0); d1 = fmaf(w3, bf2f(v3.y), d1);
    }
    for (; j < e1; ++j) {
        int s = csrc16[j];
        float w = dinv[s];
        ushort2 v = *reinterpret_cast<const ushort2*>(y + (size_t)s * HDIM + lane * 2);
        a0 = fmaf(w, bf2f(v.x), a0); a1 = fmaf(w, bf2f(v.y), a1);
    }
    float di = dinv[node];
    ushort2 vs = *reinterpret_cast<const ushort2*>(y + (size_t)node * HDIM + lane * 2);
    a0 = fmaf(di, bf2f(vs.x), a0); a1 = fmaf(di, bf2f(vs.y), a1);
    float s0 = (a0 + b0) + (c0 + d0);
    float s1 = (a1 + b1) + (c1 + d1);
    float r0 = fmaxf(fmaf(s0, di, bias[lane * 2]),     0.f);
    float r1 = fmaxf(fmaf(s1, di, bias[lane * 2 + 1]), 0.f);
    ushort2 res; res.x = f2bf(r0); res.y = f2bf(r1);
    *reinterpret_cast<ushort2*>(h + (size_t)node * HDIM + lane * 2) = res;
}

// ---------------- mean-pool: sorted batch, run-length partial sums -----------
__global__ __launch_bounds__(256) void k_pool(const ushort* __restrict__ h2,
                                              const ushort* __restrict__ h1,
                                              const int* __restrict__ batch,
                                              float* __restrict__ hG) {
    int f  = threadIdx.x;                       // 0..255 (h2 | h1 concat)
    const ushort* srcp = (f < HDIM) ? h2 : h1;
    int ff = f & (HDIM - 1);
    int n0 = blockIdx.x * 64;
    int n1 = min(n0 + 64, N_NODES);
    int g = batch[n0];
    float run = 0.f;
    for (int n = n0; n < n1; ++n) {
        int gn = batch[n];
        if (gn != g) {
            atomicAdd(&hG[g * 256 + f], run);
            run = 0.f;
            g = gn;
        }
        run += bf2f(srcp[(size_t)n * HDIM + ff]);
    }
    atomicAdd(&hG[g * 256 + f], run);
}

// ---------------- finalize: counts via binary search (batch sorted) ----------
__global__ __launch_bounds__(256) void k_final(const float* __restrict__ hG,
                                               const int* __restrict__ batch,
                                               const float* __restrict__ Wl,
                                               const float* __restrict__ bl,
                                               float* __restrict__ outp) {
    __shared__ float sH[NGRAPH * 2 * HDIM];
    __shared__ float sL[NGRAPH * NCLS];
    __shared__ int   sStart[NGRAPH + 1];
    int tid = threadIdx.x;
    if (tid <= NGRAPH) {
        int lo = 0, hi = N_NODES;
        while (lo < hi) {
            int mid = (lo + hi) >> 1;
            if (batch[mid] < tid) lo = mid + 1; else hi = mid;
        }
        sStart[tid] = lo;
    }
    __syncthreads();
    for (int i = tid; i < NGRAPH * 2 * HDIM; i += 256) {
        int g = i >> 8;
        float cnt = (float)(sStart[g + 1] - sStart[g]);
        float m = hG[i] / fmaxf(cnt, 1.0f);
        sH[i] = m;
        outp[i] = m;
    }
    __syncthreads();
    if (tid < NGRAPH * NCLS) {
        int g = tid / NCLS, c = tid % NCLS;
        float acc = bl[c];
        for (int k = 0; k < 2 * HDIM; ++k)
            acc += sH[g * 256 + k] * Wl[k * NCLS + c];
        sL[tid] = acc;
    }
    __syncthreads();
    if (tid < NGRAPH) {
        float mx = -1e30f;
        for (int c = 0; c < NCLS; ++c) mx = fmaxf(mx, sL[tid * NCLS + c]);
        float se = 0.f;
        for (int c = 0; c < NCLS; ++c) se += expf(sL[tid * NCLS + c] - mx);
        float lse = logf(se) + mx;
        for (int c = 0; c < NCLS; ++c)
            outp[NGRAPH * 2 * HDIM + tid * NCLS + c] = sL[tid * NCLS + c] - lse;
    }
}

extern "C" void kernel_launch(void* const* d_in, const int* in_sizes, int n_in,
                              void* d_out, int out_size, void* d_ws, size_t ws_size,
                              hipStream_t stream) {
    const float* x    = (const float*)d_in[0];
    const int*   eidx = (const int*)d_in[1];
    const int*   batch= (const int*)d_in[2];
    const float* W1   = (const float*)d_in[3];
    const float* b1   = (const float*)d_in[4];
    const float* W2   = (const float*)d_in[5];
    const float* b2   = (const float*)d_in[6];
    const float* Wl   = (const float*)d_in[7];
    const float* bl   = (const float*)d_in[8];
    float* outp = (float*)d_out;

    const int* src = eidx;             // edge_index[0]
    const int* dst = eidx + N_EDGES;   // edge_index[1]

    char* ws = (char*)d_ws;
    size_t off = 0;
    auto alloc = [&](size_t bytes) -> char* {
        char* p = ws + off;
        off += (bytes + 255) & ~(size_t)255;
        return p;
    };
    ushort* xb    = (ushort*)alloc((size_t)N_NODES * HDIM * 2);
    ushort* y     = (ushort*)alloc((size_t)N_NODES * HDIM * 2);
    ushort* h1    = (ushort*)alloc((size_t)N_NODES * HDIM * 2);
    ushort* h2    = (ushort*)alloc((size_t)N_NODES * HDIM * 2);
    ushort* Wt1   = (ushort*)alloc((size_t)HDIM * HDIM * 2);
    ushort* Wt2   = (ushort*)alloc((size_t)HDIM * HDIM * 2);
    float*  dinv  = (float*) alloc((size_t)N_NODES * 4);
    int*    cnti  = (int*)   alloc((size_t)N_NODES * 4);
    int*    rowptr= (int*)   alloc((size_t)(N_NODES + 1) * 4);
    int*    bsum  = (int*)   alloc((size_t)NSCANBLK * 4);
    ushort* slot16= (ushort*)alloc((size_t)N_EDGES * 2);
    ushort* csrc16= (ushort*)alloc((size_t)N_EDGES * 2);
    float*  hG    = (float*) alloc((size_t)NGRAPH * 2 * HDIM * 4);

    k_pre  <<<(N_NODES * HDIM / 8 + 255) / 256, 256, 0, stream>>>(x, xb, W1, W2, Wt1, Wt2, cnti, hG);
    k_count<<<NB_EDGE, 256, 0, stream>>>(dst, cnti, slot16);
    k_scan1<<<NSCANBLK, 256, 0, stream>>>(cnti, rowptr, bsum, dinv);
    k_scan2<<<1, 64, 0, stream>>>(bsum, rowptr);
    k_scan3<<<(N_NODES + 255) / 256, 256, 0, stream>>>(rowptr, bsum);

    // gemm1 (independent of CSR) fused with fill (depends on scan3) — overlap
    k_gemm_fill<<<NB_GEMM + NB_EDGE, 256, 0, stream>>>(xb, Wt1, y,
                                                       src, dst, rowptr, slot16, csrc16);
    k_agg <<<(N_NODES + 3) / 4, 256, 0, stream>>>(y, rowptr, csrc16, dinv, b1, h1);
    k_gemm<<<NB_GEMM, 256, 0, stream>>>(h1, Wt2, y);
    k_agg <<<(N_NODES + 3) / 4, 256, 0, stream>>>(y, rowptr, csrc16, dinv, b2, h2);

    k_pool <<<(N_NODES + 63) / 64, 256, 0, stream>>>(h2, h1, batch, hG);
    k_final<<<1, 256, 0, stream>>>(hG, batch, Wl, bl, outp);

    (void)in_sizes; (void)n_in; (void)out_size; (void)ws_size;
}